// Round 14
// baseline (220.319 us; speedup 1.0000x reference)
//
#include <hip/hip_runtime.h>

// RGCN restructured:
//   out1 = A @ W1,   A[i, r*N+j] = adj[r,i,j]   (6144 x 12288) @ (12288 x 256)
//   out2 = A @ Y,    Y[r*N+j, h] = (relu(out1) @ W2_r)[j,h]
//   final[h] = sum_i out1[i,h] ; final[256+h] = sum_i out2[i,h]
// R14 = identical resubmission of R13 (container died pre-run, same sick pod
// as R6). B-direct-from-L2 in the gemm_adj family (LDS 104->40 KB per
// block-K-step) using BUILTIN MFMA (hazard recognizer sees VMEM->MFMA deps;
// R6-R8's NaN attributed to inline-asm MFMA losing that protection).
// B fragment addresses byte-identical to the old staged Blds reads.

#define NN 6144
#define HH 256
#define SPLIT 8
#define KCHUNK 1536   // (2*NN)/SPLIT
#define KSTEPS 24     // KCHUNK/64

typedef __attribute__((ext_vector_type(4))) float f32x4;
typedef __attribute__((ext_vector_type(8))) unsigned short u16x8;
typedef __attribute__((ext_vector_type(8))) short s16x8;
typedef __attribute__((ext_vector_type(4))) unsigned short u16x4;

__device__ __forceinline__ unsigned short f2bf(float f) {
  unsigned int u = __float_as_uint(f);
  u += 0x7FFFu + ((u >> 16) & 1u);   // RNE
  return (unsigned short)(u >> 16);
}
__device__ __forceinline__ float bf2f(unsigned short h) {
  return __uint_as_float(((unsigned int)h) << 16);
}

// asm MFMA (validated; used by gemm_y only)
__device__ __forceinline__ void mfma_bf16(f32x4& d, u16x8 a, u16x8 b) {
  asm("v_mfma_f32_16x16x32_bf16 %0, %1, %2, %0" : "+v"(d) : "v"(a), "v"(b));
}
// builtin MFMA (compiler-visible; used by gemm_adj family)
__device__ __forceinline__ void mfma_bf16b(f32x4& d, u16x8 a, u16x8 b) {
  d = __builtin_amdgcn_mfma_f32_16x16x32_bf16(
        __builtin_bit_cast(s16x8, a), __builtin_bit_cast(s16x8, b), d, 0, 0, 0);
}

// Raw barriers (T4, validated R9): no vmcnt drain across K-steps.
#define BAR_PRE_STAGE()   asm volatile("s_barrier" ::: "memory")
#define BAR_PRE_COMPUTE() asm volatile("s_waitcnt lgkmcnt(0)\n\ts_barrier" ::: "memory")

// ---------------------------------------------------------------------------
// prep: fused {zero fin} + {wgen W1: 192 tiles} + {wgen W2: 8 tiles}.
// out[t*2048 + h*8 + sp] holds W[k = t*64 + (sp^(h&7))*8 + e][h]  (validated)
// ---------------------------------------------------------------------------
__global__ void prep_kernel(const float* __restrict__ bw1, const float* __restrict__ bc1,
                            const float* __restrict__ bw2, const float* __restrict__ bc2,
                            unsigned short* __restrict__ B1ws, unsigned short* __restrict__ w2ws,
                            float* __restrict__ fin)
{
  const int b   = blockIdx.x;
  const int tid = threadIdx.x;
  if (b >= 200) { fin[(b - 200) * 256 + tid] = 0.f; return; }

  const float* basis; const float* bc; unsigned short* outw;
  int tilesPerR, jdim, t;
  if (b < 192) { basis = bw1; bc = bc1; outw = B1ws; tilesPerR = 96; jdim = NN; t = b; }
  else         { basis = bw2; bc = bc2; outw = w2ws; tilesPerR = 4;  jdim = HH; t = b - 192; }

  __shared__ unsigned short wt[64][265];
  const int r  = t / tilesPerR;
  const int jt = t % tilesPerR;
  const float c0 = bc[r * 2 + 0];
  const float c1 = bc[r * 2 + 1];
  const float* b0 = basis + (size_t)jt * 64 * HH;
  const float* b1 = basis + (size_t)jdim * HH + (size_t)jt * 64 * HH;
#pragma unroll
  for (int k = 0; k < 16; ++k) {
    int idx = tid + k * 256;
    int row = idx >> 6;
    int c4  = (idx & 63) * 4;
    f32x4 v0 = *(const f32x4*)(b0 + (size_t)row * HH + c4);
    f32x4 v1 = *(const f32x4*)(b1 + (size_t)row * HH + c4);
    wt[row][c4 + 0] = f2bf(c0 * v0.x + c1 * v1.x);
    wt[row][c4 + 1] = f2bf(c0 * v0.y + c1 * v1.y);
    wt[row][c4 + 2] = f2bf(c0 * v0.z + c1 * v1.z);
    wt[row][c4 + 3] = f2bf(c0 * v0.w + c1 * v1.w);
  }
  __syncthreads();
#pragma unroll
  for (int k = 0; k < 8; ++k) {
    int chunk = tid + k * 256;
    int h  = chunk >> 3;
    int sp = chunk & 7;
    int j0 = (sp ^ (h & 7)) * 8;
    u16x8 v;
#pragma unroll
    for (int e = 0; e < 8; ++e) v[e] = wt[j0 + e][h];
    *(u16x8*)(outw + ((size_t)t * 2048 + chunk) * 8) = v;
  }
}

// ---------------------------------------------------------------------------
// Shared macros for the gemm_adj family (BM=64, BN=256, BK=64).
// B fragments direct from ws: byte = (tBase+KK)*32768 + row*128 + off  —
// identical bytes to the old Blds[row*128+off] after the identity copy.
// ---------------------------------------------------------------------------
#define GEMM_PROLOGUE_COMMON()                                                 \
  const int tid  = threadIdx.x;                                                \
  const int lane = tid & 63;                                                   \
  const int wave = tid >> 6;                                                   \
  const int bid  = blockIdx.x;                                                 \
  const int s    = bid & 7;          /* XCD-affine (validated R10) */          \
  const int mb   = bid >> 3;                                                   \
  const int i0 = mb * 64;                                                      \
  const int kbase = s * KCHUNK;                                                \
  const int tBase = kbase / 64;                                                \
  const char* bTile0 = (const char*)Bws + ((size_t)tBase << 15);

#define DECL_ACC()                                                             \
  f32x4 acc[4][4];                                                             \
  _Pragma("unroll")                                                            \
  for (int m = 0; m < 4; ++m)                                                  \
    _Pragma("unroll")                                                          \
    for (int n = 0; n < 4; ++n) acc[m][n] = (f32x4){0.f, 0.f, 0.f, 0.f};

#define ISSUE_BF(SET, KS, KK) do {                                             \
    const char* bt = bTile0 + ((size_t)(KK) << 15);                            \
    _Pragma("unroll")                                                          \
    for (int n = 0; n < 4; ++n) {                                              \
      int row = wave * 64 + n * 16 + (lane & 15);                              \
      int off = ((KS) * 64 + ((lane >> 4) << 4)) ^ ((row & 7) << 4);           \
      SET[n] = *(const u16x8*)(bt + row * 128 + off);                          \
    } } while (0)

#define COMPUTE_HALF(KS, BSET) do {                                            \
    u16x8 af[4];                                                               \
    _Pragma("unroll")                                                          \
    for (int m = 0; m < 4; ++m) {                                              \
      int row = m * 16 + (lane & 15);                                          \
      int off = ((KS) * 64 + ((lane >> 4) << 4)) ^ ((row & 7) << 4);           \
      af[m] = *(const u16x8*)((const char*)Alds + row * 128 + off);            \
    }                                                                          \
    _Pragma("unroll")                                                          \
    for (int m = 0; m < 4; ++m)                                                \
      _Pragma("unroll")                                                        \
      for (int n = 0; n < 4; ++n)                                              \
        mfma_bf16b(acc[m][n], af[m], BSET[n]);                                 \
  } while (0)

#define WRITE_P() do {                                                         \
    unsigned short* P = Pp + ((size_t)s * NN + i0) * HH;                       \
    _Pragma("unroll")                                                          \
    for (int m = 0; m < 4; ++m)                                                \
      _Pragma("unroll")                                                        \
      for (int n = 0; n < 4; ++n) {                                            \
        int col = wave * 64 + n * 16 + (lane & 15);                            \
        _Pragma("unroll")                                                      \
        for (int q = 0; q < 4; ++q) {                                          \
          int row = m * 16 + ((lane >> 4) << 2) + q;                           \
          P[(size_t)row * HH + col] = f2bf(acc[m][n][q]);                      \
        }                                                                      \
      } } while (0)

#define ISSUE_A(SET, KK) do {                                                  \
    _Pragma("unroll")                                                          \
    for (int it = 0; it < 4; ++it)                                             \
      SET[it] = *(const f32x4*)(aRow + (size_t)it * 16 * NN + (KK) * 64);      \
  } while (0)

// ---------------------------------------------------------------------------
// gemm_adj_store: fp32 adj in; also stores the converted+swizzled Alds image
// (8 KB per K-step) to Aws for gemm2.
// ---------------------------------------------------------------------------
__global__ __launch_bounds__(256, 3) void gemm_adj_store_kernel(
    const float* __restrict__ adj, const unsigned short* __restrict__ Bws,
    unsigned short* __restrict__ Pp, unsigned short* __restrict__ Aws)
{
  __shared__ __align__(16) unsigned short Alds[64 * 64];
  GEMM_PROLOGUE_COMMON();
  const int rrel = kbase / NN;
  const int jb   = kbase % NN;
  const float* aRow = adj + (size_t)rrel * NN * NN
                      + (size_t)(i0 + (tid >> 4)) * NN + jb + (tid & 15) * 4;
  char* aTile0 = (char*)Aws + ((size_t)(s * 96 + mb) * 24) * 8192;

  DECL_ACC();
  f32x4 av0[4], av1[4];
  u16x8 bf0[4], bf1[4];

#define STAGE_A_ST(SET, KK) do {                                               \
    char* at = aTile0 + (size_t)(KK) * 8192;                                   \
    _Pragma("unroll")                                                          \
    for (int it = 0; it < 4; ++it) {                                           \
      int row = (tid >> 4) + it * 16;                                          \
      int off = ((tid & 15) * 8) ^ ((row & 7) << 4);                           \
      u16x4 w;                                                                 \
      w[0] = f2bf(SET[it].x); w[1] = f2bf(SET[it].y);                          \
      w[2] = f2bf(SET[it].z); w[3] = f2bf(SET[it].w);                          \
      *(u16x4*)((char*)Alds + row * 128 + off) = w;                            \
      *(u16x4*)(at + row * 128 + off) = w;                                     \
    } } while (0)

  ISSUE_A(av0, 0);
  ISSUE_A(av1, 1);
  ISSUE_BF(bf0, 0, 0);
  ISSUE_BF(bf1, 1, 0);

  for (int kk = 0; kk < KSTEPS; kk += 2) {
    // ---- even ----
    BAR_PRE_STAGE();
    STAGE_A_ST(av0, kk);
    BAR_PRE_COMPUTE();
    COMPUTE_HALF(0, bf0);
    ISSUE_BF(bf0, 0, kk + 1);               // kk+1 <= 23 always (kk even)
    COMPUTE_HALF(1, bf1);
    ISSUE_BF(bf1, 1, kk + 1);
    // ---- odd ----
    BAR_PRE_STAGE();
    STAGE_A_ST(av1, kk + 1);
    BAR_PRE_COMPUTE();
    if (kk + 2 < KSTEPS) {
      ISSUE_A(av0, kk + 2);
      ISSUE_A(av1, kk + 3);
    }
    COMPUTE_HALF(0, bf0);
    if (kk + 2 < KSTEPS) ISSUE_BF(bf0, 0, kk + 2);
    COMPUTE_HALF(1, bf1);
    if (kk + 2 < KSTEPS) ISSUE_BF(bf1, 1, kk + 2);
  }
#undef STAGE_A_ST
  WRITE_P();
}

// ---------------------------------------------------------------------------
// gemm_adj_bf: bf16 A-tiles in (exact Alds images) -> linear identity copy.
// ---------------------------------------------------------------------------
__global__ __launch_bounds__(256, 3) void gemm_adj_bf_kernel(
    const unsigned short* __restrict__ Aws, const unsigned short* __restrict__ Bws,
    unsigned short* __restrict__ Pp)
{
  __shared__ __align__(16) unsigned short Alds[64 * 64];
  GEMM_PROLOGUE_COMMON();
  const char* aTile0 = (const char*)Aws + ((size_t)(s * 96 + mb) * 24) * 8192;

  DECL_ACC();
  u16x8 av0[2], av1[2];
  u16x8 bf0[4], bf1[4];

#define ISSUE_A2(SET, KK) do {                                                 \
    const char* at = aTile0 + (size_t)(KK) * 8192 + (size_t)tid * 32;          \
    SET[0] = *(const u16x8*)(at);                                              \
    SET[1] = *(const u16x8*)(at + 16);                                         \
  } while (0)

#define STAGE_A2(SET) do {                                                     \
    *(u16x8*)((char*)Alds + (size_t)tid * 32) = SET[0];                        \
    *(u16x8*)((char*)Alds + (size_t)tid * 32 + 16) = SET[1];                   \
  } while (0)

  ISSUE_A2(av0, 0);
  ISSUE_A2(av1, 1);
  ISSUE_BF(bf0, 0, 0);
  ISSUE_BF(bf1, 1, 0);

  for (int kk = 0; kk < KSTEPS; kk += 2) {
    // ---- even ----
    BAR_PRE_STAGE();
    STAGE_A2(av0);
    BAR_PRE_COMPUTE();
    COMPUTE_HALF(0, bf0);
    ISSUE_BF(bf0, 0, kk + 1);
    COMPUTE_HALF(1, bf1);
    ISSUE_BF(bf1, 1, kk + 1);
    // ---- odd ----
    BAR_PRE_STAGE();
    STAGE_A2(av1);
    BAR_PRE_COMPUTE();
    if (kk + 2 < KSTEPS) {
      ISSUE_A2(av0, kk + 2);
      ISSUE_A2(av1, kk + 3);
    }
    COMPUTE_HALF(0, bf0);
    if (kk + 2 < KSTEPS) ISSUE_BF(bf0, 0, kk + 2);
    COMPUTE_HALF(1, bf1);
    if (kk + 2 < KSTEPS) ISSUE_BF(bf1, 1, kk + 2);
  }
#undef ISSUE_A2
#undef STAGE_A2
  WRITE_P();
}

// ---------------------------------------------------------------------------
// gemm_adj: fallback (fp32 A, no store), same B-direct structure.
// ---------------------------------------------------------------------------
__global__ __launch_bounds__(256, 3) void gemm_adj_kernel(
    const float* __restrict__ adj, const unsigned short* __restrict__ Bws,
    unsigned short* __restrict__ Pp)
{
  __shared__ __align__(16) unsigned short Alds[64 * 64];
  GEMM_PROLOGUE_COMMON();
  const int rrel = kbase / NN;
  const int jb   = kbase % NN;
  const float* aRow = adj + (size_t)rrel * NN * NN
                      + (size_t)(i0 + (tid >> 4)) * NN + jb + (tid & 15) * 4;

  DECL_ACC();
  f32x4 av0[4], av1[4];
  u16x8 bf0[4], bf1[4];

#define STAGE_A(SET) do {                                                      \
    _Pragma("unroll")                                                          \
    for (int it = 0; it < 4; ++it) {                                           \
      int row = (tid >> 4) + it * 16;                                          \
      int off = ((tid & 15) * 8) ^ ((row & 7) << 4);                           \
      u16x4 w;                                                                 \
      w[0] = f2bf(SET[it].x); w[1] = f2bf(SET[it].y);                          \
      w[2] = f2bf(SET[it].z); w[3] = f2bf(SET[it].w);                          \
      *(u16x4*)((char*)Alds + row * 128 + off) = w;                            \
    } } while (0)

  ISSUE_A(av0, 0);
  ISSUE_A(av1, 1);
  ISSUE_BF(bf0, 0, 0);
  ISSUE_BF(bf1, 1, 0);

  for (int kk = 0; kk < KSTEPS; kk += 2) {
    BAR_PRE_STAGE();
    STAGE_A(av0);
    BAR_PRE_COMPUTE();
    COMPUTE_HALF(0, bf0);
    ISSUE_BF(bf0, 0, kk + 1);
    COMPUTE_HALF(1, bf1);
    ISSUE_BF(bf1, 1, kk + 1);
    BAR_PRE_STAGE();
    STAGE_A(av1);
    BAR_PRE_COMPUTE();
    if (kk + 2 < KSTEPS) {
      ISSUE_A(av0, kk + 2);
      ISSUE_A(av1, kk + 3);
    }
    COMPUTE_HALF(0, bf0);
    if (kk + 2 < KSTEPS) ISSUE_BF(bf0, 0, kk + 2);
    COMPUTE_HALF(1, bf1);
    if (kk + 2 < KSTEPS) ISSUE_BF(bf1, 1, kk + 2);
  }
#undef STAGE_A
  WRITE_P();
}

// ---------------------------------------------------------------------------
// gemm_y: Y_r = x @ W2_r (K=256). Output written in B-operand layout.
// (verbatim validated R5/R9 kernel, asm MFMA)
// ---------------------------------------------------------------------------
__global__ __launch_bounds__(256, 2) void gemm_y_kernel(
    const unsigned short* __restrict__ xws, const unsigned short* __restrict__ w2ws,
    unsigned short* __restrict__ B2ws)
{
  __shared__ __align__(16) unsigned short Alds[64 * 64];
  __shared__ __align__(16) unsigned short Blds[256 * 64];
  const int tid  = threadIdx.x;
  const int lane = tid & 63;
  const int wave = tid >> 6;
  const int mb = blockIdx.x;
  const int r  = blockIdx.y;

  f32x4 acc[4][4];
#pragma unroll
  for (int m = 0; m < 4; ++m)
#pragma unroll
    for (int n = 0; n < 4; ++n) acc[m][n] = (f32x4){0.f, 0.f, 0.f, 0.f};

  for (int dt = 0; dt < 4; ++dt) {
    u16x8 avv[2];
    avv[0] = *(const u16x8*)(xws + (((size_t)(mb * 4 + dt)) * 512 + tid) * 8);
    avv[1] = *(const u16x8*)(xws + (((size_t)(mb * 4 + dt)) * 512 + 256 + tid) * 8);
    u16x8 bv[8];
#pragma unroll
    for (int c = 0; c < 8; ++c)
      bv[c] = *(const u16x8*)(w2ws + (((size_t)(r * 4 + dt)) * 2048 + c * 256 + tid) * 8);
    __syncthreads();
    *(u16x8*)(Alds + (size_t)tid * 8) = avv[0];
    *(u16x8*)(Alds + ((size_t)256 + tid) * 8) = avv[1];
#pragma unroll
    for (int c = 0; c < 8; ++c)
      *(u16x8*)(Blds + ((size_t)c * 256 + tid) * 8) = bv[c];
    __syncthreads();
#pragma unroll
    for (int ks = 0; ks < 2; ++ks) {
      u16x8 af[4], bfr[4];
#pragma unroll
      for (int m = 0; m < 4; ++m) {
        int row = m * 16 + (lane & 15);
        int off = (ks * 64 + ((lane >> 4) << 4)) ^ ((row & 7) << 4);
        af[m] = *(const u16x8*)((const char*)Alds + row * 128 + off);
      }
#pragma unroll
      for (int n = 0; n < 4; ++n) {
        int row = wave * 64 + n * 16 + (lane & 15);
        int off = (ks * 64 + ((lane >> 4) << 4)) ^ ((row & 7) << 4);
        bfr[n] = *(const u16x8*)((const char*)Blds + row * 128 + off);
      }
#pragma unroll
      for (int m = 0; m < 4; ++m)
#pragma unroll
        for (int n = 0; n < 4; ++n)
          mfma_bf16(acc[m][n], af[m], bfr[n]);
    }
  }
  // emit Y in B-operand layout: chunk(t=r*96+mb, h, pos) gets k-slot pos^(h&7)
  const int tg = r * 96 + mb;
#pragma unroll
  for (int m = 0; m < 4; ++m) {
    int scont = m * 2 + ((lane >> 4) >> 1);
    int e0    = ((lane >> 4) & 1) * 4;
#pragma unroll
    for (int n = 0; n < 4; ++n) {
      int h   = wave * 64 + n * 16 + (lane & 15);
      int pos = scont ^ (h & 7);
      u16x4 v;
      v[0] = f2bf(acc[m][n][0]); v[1] = f2bf(acc[m][n][1]);
      v[2] = f2bf(acc[m][n][2]); v[3] = f2bf(acc[m][n][3]);
      *(u16x4*)(B2ws + (((size_t)tg * 2048 + h * 8 + pos) * 8 + e0)) = v;
    }
  }
}

// ---------------------------------------------------------------------------
// reduce1: sum_s P[s] -> x = relu -> bf16 pre-swizzled A-tiles (xws)
//          + fused column-sum of out1 into fin[0..255]
// ---------------------------------------------------------------------------
__global__ void reduce1_kernel(const unsigned short* __restrict__ Pp,
                               unsigned short* __restrict__ xws,
                               float* __restrict__ fin)
{
  __shared__ float csm[8][256];
  const int tid = threadIdx.x;
  const int b   = blockIdx.x;
  const int hc  = tid & 31;
  const int rg  = tid >> 5;
  const int dt    = hc >> 3;
  const int scont = hc & 7;
  float cs[8] = {0.f, 0.f, 0.f, 0.f, 0.f, 0.f, 0.f, 0.f};
  for (int k = 0; k < 8; ++k) {
    int i = b * 64 + rg + k * 8;
    float sv[8] = {0.f, 0.f, 0.f, 0.f, 0.f, 0.f, 0.f, 0.f};
#pragma unroll
    for (int s = 0; s < SPLIT; ++s) {
      u16x8 v = *(const u16x8*)(Pp + ((size_t)s * NN + i) * HH + hc * 8);
#pragma unroll
      for (int e = 0; e < 8; ++e) sv[e] += bf2f(v[e]);
    }
    u16x8 xv;
#pragma unroll
    for (int e = 0; e < 8; ++e) {
      cs[e] += sv[e];
      xv[e] = f2bf(fmaxf(sv[e], 0.f));
    }
    int pos = scont ^ (i & 7);
    *(u16x8*)(xws + (((size_t)(b * 4 + dt)) * 512 + (i & 63) * 8 + pos) * 8) = xv;
  }
#pragma unroll
  for (int e = 0; e < 8; ++e) csm[rg][hc * 8 + e] = cs[e];
  __syncthreads();
  float v = 0.f;
#pragma unroll
  for (int r8 = 0; r8 < 8; ++r8) v += csm[r8][tid];
  atomicAdd(&fin[tid], v);
}

// reduce2: sum_s P[s] -> out2 fp32 + fused column-sum into fin[256..511]
__global__ void reduce2_kernel(const unsigned short* __restrict__ Pp,
                               float* __restrict__ outp,
                               float* __restrict__ fin)
{
  __shared__ float csm[8][256];
  const int tid = threadIdx.x;
  const int b   = blockIdx.x;
  const int hc  = tid & 31;
  const int rg  = tid >> 5;
  float cs[8] = {0.f, 0.f, 0.f, 0.f, 0.f, 0.f, 0.f, 0.f};
  for (int k = 0; k < 8; ++k) {
    int i = b * 64 + rg + k * 8;
    float sv[8] = {0.f, 0.f, 0.f, 0.f, 0.f, 0.f, 0.f, 0.f};
#pragma unroll
    for (int s = 0; s < SPLIT; ++s) {
      u16x8 v = *(const u16x8*)(Pp + ((size_t)s * NN + i) * HH + hc * 8);
#pragma unroll
      for (int e = 0; e < 8; ++e) sv[e] += bf2f(v[e]);
    }
    float* o = outp + (size_t)i * HH + hc * 8;
    *(f32x4*)o = (f32x4){sv[0], sv[1], sv[2], sv[3]};
    *(f32x4*)(o + 4) = (f32x4){sv[4], sv[5], sv[6], sv[7]};
#pragma unroll
    for (int e = 0; e < 8; ++e) cs[e] += sv[e];
  }
#pragma unroll
  for (int e = 0; e < 8; ++e) csm[rg][hc * 8 + e] = cs[e];
  __syncthreads();
  float v = 0.f;
#pragma unroll
  for (int r8 = 0; r8 < 8; ++r8) v += csm[r8][tid];
  atomicAdd(&fin[256 + tid], v);
}

// ---------------------------------------------------------------------------
extern "C" void kernel_launch(void* const* d_in, const int* in_sizes, int n_in,
                              void* d_out, int out_size, void* d_ws, size_t ws_size,
                              hipStream_t stream)
{
  const float* adj = (const float*)d_in[0];
  const float* bw1 = (const float*)d_in[1];
  const float* bc1 = (const float*)d_in[2];
  const float* bw2 = (const float*)d_in[3];
  const float* bc2 = (const float*)d_in[4];
  float* out2 = (float*)d_out;                       // 6144*256 fp32
  float* fin  = (float*)d_out + (size_t)NN * HH;     // 512 fp32

  char* ws = (char*)d_ws;
  unsigned short* Pp   = (unsigned short*)(ws + 0);          // 25165824 B
  unsigned short* B1ws = (unsigned short*)(ws + 25165824);   //  6291456 B
  unsigned short* B2ws = (unsigned short*)(ws + 31457280);   //  6291456 B
  unsigned short* xws  = (unsigned short*)(ws + 37748736);   //  3145728 B
  unsigned short* w2ws = (unsigned short*)(ws + 40894464);   //   262144 B
  unsigned short* Aws  = (unsigned short*)(ws + 41943040);   // 150994944 B (end 192937984)
  const bool handoff = (ws_size >= (size_t)192937984);

  prep_kernel<<<202, 256, 0, stream>>>(bw1, bc1, bw2, bc2, B1ws, w2ws, fin);
  if (handoff)
    gemm_adj_store_kernel<<<768, 256, 0, stream>>>(adj, B1ws, Pp, Aws);
  else
    gemm_adj_kernel<<<768, 256, 0, stream>>>(adj, B1ws, Pp);
  reduce1_kernel<<<96, 256, 0, stream>>>(Pp, xws, fin);
  gemm_y_kernel<<<dim3(96, 2), 256, 0, stream>>>(xws, w2ws, B2ws);
  if (handoff)
    gemm_adj_bf_kernel<<<768, 256, 0, stream>>>(Aws, B2ws, Pp);
  else
    gemm_adj_kernel<<<768, 256, 0, stream>>>(adj, B2ws, Pp);
  reduce2_kernel<<<96, 256, 0, stream>>>(Pp, out2, fin);
}

// Round 17
// 203.472 us; speedup vs baseline: 1.0828x; 1.0828x over previous
//
#include <hip/hip_runtime.h>

// RGCN restructured:
//   out1 = A @ W1,   A[i, r*N+j] = adj[r,i,j]   (6144 x 12288) @ (12288 x 256)
//   out2 = A @ Y,    Y[r*N+j, h] = (relu(out1) @ W2_r)[j,h]
//   final[h] = sum_i out1[i,h] ; final[256+h] = sum_i out2[i,h]
// R17 = identical resubmission of R15/R16 (container unresponsive pre-run,
// 4th infra failure on pod clean-best-rude-plate). R15 = R12 base +
// FRAGMENT-ORDER B1ws: prep emits W1 tiles so each wave's B fragment load is
// one contiguous 1KB instruction; gemm1 consumes B direct from L2 (no Blds;
// LDS 104->40KB per block-K-step) with builtin MFMA (hazard-safe per R14).
// gemm2/gemm_y/reduces verbatim R12 (validated).

#define NN 6144
#define HH 256
#define SPLIT 8
#define KCHUNK 1536   // (2*NN)/SPLIT
#define KSTEPS 24     // KCHUNK/64

typedef __attribute__((ext_vector_type(4))) float f32x4;
typedef __attribute__((ext_vector_type(8))) unsigned short u16x8;
typedef __attribute__((ext_vector_type(8))) short s16x8;
typedef __attribute__((ext_vector_type(4))) unsigned short u16x4;

__device__ __forceinline__ unsigned short f2bf(float f) {
  unsigned int u = __float_as_uint(f);
  u += 0x7FFFu + ((u >> 16) & 1u);   // RNE
  return (unsigned short)(u >> 16);
}
__device__ __forceinline__ float bf2f(unsigned short h) {
  return __uint_as_float(((unsigned int)h) << 16);
}

// asm MFMA (validated; gemm2 + gemm_y)
__device__ __forceinline__ void mfma_bf16(f32x4& d, u16x8 a, u16x8 b) {
  asm("v_mfma_f32_16x16x32_bf16 %0, %1, %2, %0" : "+v"(d) : "v"(a), "v"(b));
}
// builtin MFMA (compiler-visible hazards; gemm1 with direct-global B)
__device__ __forceinline__ void mfma_bf16b(f32x4& d, u16x8 a, u16x8 b) {
  d = __builtin_amdgcn_mfma_f32_16x16x32_bf16(
        __builtin_bit_cast(s16x8, a), __builtin_bit_cast(s16x8, b), d, 0, 0, 0);
}

// Raw barriers (T4, validated R9): no vmcnt drain across K-steps.
#define BAR_PRE_STAGE()   asm volatile("s_barrier" ::: "memory")
#define BAR_PRE_COMPUTE() asm volatile("s_waitcnt lgkmcnt(0)\n\ts_barrier" ::: "memory")

// ---------------------------------------------------------------------------
// prep: fused {zero fin} + {wgen W1 -> FRAGMENT order} + {wgen W2 -> old
// swizzled order (validated, consumed by gemm_y)}.
// ---------------------------------------------------------------------------
__global__ void prep_kernel(const float* __restrict__ bw1, const float* __restrict__ bc1,
                            const float* __restrict__ bw2, const float* __restrict__ bc2,
                            unsigned short* __restrict__ B1ws, unsigned short* __restrict__ w2ws,
                            float* __restrict__ fin)
{
  const int b   = blockIdx.x;
  const int tid = threadIdx.x;
  if (b >= 200) { fin[(b - 200) * 256 + tid] = 0.f; return; }

  const float* basis; const float* bc; unsigned short* outw;
  int tilesPerR, jdim, t;
  if (b < 192) { basis = bw1; bc = bc1; outw = B1ws; tilesPerR = 96; jdim = NN; t = b; }
  else         { basis = bw2; bc = bc2; outw = w2ws; tilesPerR = 4;  jdim = HH; t = b - 192; }

  __shared__ unsigned short wt[64][265];
  const int r  = t / tilesPerR;
  const int jt = t % tilesPerR;
  const float c0 = bc[r * 2 + 0];
  const float c1 = bc[r * 2 + 1];
  const float* b0 = basis + (size_t)jt * 64 * HH;
  const float* b1 = basis + (size_t)jdim * HH + (size_t)jt * 64 * HH;
#pragma unroll
  for (int k = 0; k < 16; ++k) {
    int idx = tid + k * 256;
    int row = idx >> 6;
    int c4  = (idx & 63) * 4;
    f32x4 v0 = *(const f32x4*)(b0 + (size_t)row * HH + c4);
    f32x4 v1 = *(const f32x4*)(b1 + (size_t)row * HH + c4);
    wt[row][c4 + 0] = f2bf(c0 * v0.x + c1 * v1.x);
    wt[row][c4 + 1] = f2bf(c0 * v0.y + c1 * v1.y);
    wt[row][c4 + 2] = f2bf(c0 * v0.z + c1 * v1.z);
    wt[row][c4 + 3] = f2bf(c0 * v0.w + c1 * v1.w);
  }
  __syncthreads();
  if (b < 192) {
    // FRAGMENT order: chunk q=(w*8+ks*4+n)*64+l holds
    // W[t*64 + (ks*4+(l>>4))*8 + e][w*64 + n*16 + (l&15)]
#pragma unroll
    for (int k = 0; k < 8; ++k) {
      int q  = tid + k * 256;
      int l  = q & 63;
      int n  = (q >> 6) & 3;
      int ks = (q >> 8) & 1;
      int w  = (q >> 9) & 3;
      int kb = ks * 32 + ((l >> 4) << 3);
      int h  = w * 64 + n * 16 + (l & 15);
      u16x8 v;
#pragma unroll
      for (int e = 0; e < 8; ++e) v[e] = wt[kb + e][h];
      *(u16x8*)(outw + ((size_t)t * 2048 + q) * 8) = v;
    }
  } else {
    // old swizzled order (validated): out[t*2048+h*8+sp] = W[(sp^(h&7))*8+e][h]
#pragma unroll
    for (int k = 0; k < 8; ++k) {
      int chunk = tid + k * 256;
      int h  = chunk >> 3;
      int sp = chunk & 7;
      int j0 = (sp ^ (h & 7)) * 8;
      u16x8 v;
#pragma unroll
      for (int e = 0; e < 8; ++e) v[e] = wt[j0 + e][h];
      *(u16x8*)(outw + ((size_t)t * 2048 + chunk) * 8) = v;
    }
  }
}

// ---------------------------------------------------------------------------
// Shared pieces (BM=64, BN=256, BK=64).
// ---------------------------------------------------------------------------
#define GEMM_IDX()                                                             \
  const int tid  = threadIdx.x;                                                \
  const int lane = tid & 63;                                                   \
  const int wave = tid >> 6;                                                   \
  const int bid  = blockIdx.x;                                                 \
  const int s    = bid & 7;          /* XCD-affine (validated R10) */          \
  const int mb   = bid >> 3;                                                   \
  const int i0 = mb * 64;                                                      \
  const int kbase = s * KCHUNK;                                                \
  const int tBase = kbase / 64;

#define DECL_ACC()                                                             \
  f32x4 acc[4][4];                                                             \
  _Pragma("unroll")                                                            \
  for (int m = 0; m < 4; ++m)                                                  \
    _Pragma("unroll")                                                          \
    for (int n = 0; n < 4; ++n) acc[m][n] = (f32x4){0.f, 0.f, 0.f, 0.f};

#define WRITE_P() do {                                                         \
    unsigned short* P = Pp + ((size_t)s * NN + i0) * HH;                       \
    _Pragma("unroll")                                                          \
    for (int m = 0; m < 4; ++m)                                                \
      _Pragma("unroll")                                                        \
      for (int n = 0; n < 4; ++n) {                                            \
        int col = wave * 64 + n * 16 + (lane & 15);                            \
        _Pragma("unroll")                                                      \
        for (int q = 0; q < 4; ++q) {                                          \
          int row = m * 16 + ((lane >> 4) << 2) + q;                           \
          P[(size_t)row * HH + col] = f2bf(acc[m][n][q]);                      \
        }                                                                      \
      } } while (0)

#define ISSUE_A(SET, KK) do {                                                  \
    _Pragma("unroll")                                                          \
    for (int it = 0; it < 4; ++it)                                             \
      SET[it] = *(const f32x4*)(aRow + (size_t)it * 16 * NN + (KK) * 64);      \
  } while (0)

// gemm1: coalesced fragment-order B load (1KB per instruction per wave)
#define ISSUE_BFC(SET, KS, KK) do {                                            \
    const unsigned short* bt = bwBase + (size_t)(KK) * 2048 * 8;               \
    _Pragma("unroll")                                                          \
    for (int n = 0; n < 4; ++n)                                                \
      SET[n] = *(const u16x8*)(bt + (size_t)(((KS) * 4 + n) * 64) * 8);        \
  } while (0)

// gemm1 compute half (builtin MFMA; A from swizzled Alds)
#define COMPUTE_HALF(KS, BSET) do {                                            \
    u16x8 af[4];                                                               \
    _Pragma("unroll")                                                          \
    for (int m = 0; m < 4; ++m) {                                              \
      int row = m * 16 + (lane & 15);                                          \
      int off = ((KS) * 64 + ((lane >> 4) << 4)) ^ ((row & 7) << 4);           \
      af[m] = *(const u16x8*)((const char*)Alds + row * 128 + off);            \
    }                                                                          \
    _Pragma("unroll")                                                          \
    for (int m = 0; m < 4; ++m)                                                \
      _Pragma("unroll")                                                        \
      for (int n = 0; n < 4; ++n)                                              \
        mfma_bf16b(acc[m][n], af[m], BSET[n]);                                 \
  } while (0)

// ---------------------------------------------------------------------------
// gemm1: fp32 adj in, fragment-order B direct from L2, builtin MFMA.
// Optionally stores the converted+swizzled Alds image to Aws (handoff).
// ---------------------------------------------------------------------------
template <bool STORE>
__global__ __launch_bounds__(256, 3) void gemm1_kernel(
    const float* __restrict__ adj, const unsigned short* __restrict__ Bws,
    unsigned short* __restrict__ Pp, unsigned short* __restrict__ Aws)
{
  __shared__ __align__(16) unsigned short Alds[64 * 64];
  GEMM_IDX();
  const int rrel = kbase / NN;
  const int jb   = kbase % NN;
  const float* aRow = adj + (size_t)rrel * NN * NN
                      + (size_t)(i0 + (tid >> 4)) * NN + jb + (tid & 15) * 4;
  const unsigned short* bwBase = Bws + ((size_t)tBase * 2048 + (size_t)wave * 512 + lane) * 8;
  char* aTile0 = (char*)Aws + ((size_t)(s * 96 + mb) * 24) * 8192;

  DECL_ACC();
  f32x4 av0[4], av1[4];
  u16x8 bf0[4], bf1[4];

#define STAGE_A1(SET, KK) do {                                                 \
    char* at = aTile0 + (size_t)(KK) * 8192;                                   \
    _Pragma("unroll")                                                          \
    for (int it = 0; it < 4; ++it) {                                           \
      int row = (tid >> 4) + it * 16;                                          \
      int off = ((tid & 15) * 8) ^ ((row & 7) << 4);                           \
      u16x4 w;                                                                 \
      w[0] = f2bf(SET[it].x); w[1] = f2bf(SET[it].y);                          \
      w[2] = f2bf(SET[it].z); w[3] = f2bf(SET[it].w);                          \
      *(u16x4*)((char*)Alds + row * 128 + off) = w;                            \
      if (STORE) *(u16x4*)(at + row * 128 + off) = w;                          \
    } } while (0)

  ISSUE_A(av0, 0);
  ISSUE_A(av1, 1);
  ISSUE_BFC(bf0, 0, 0);
  ISSUE_BFC(bf1, 1, 0);

  for (int kk = 0; kk < KSTEPS; kk += 2) {
    // ---- even ----
    BAR_PRE_STAGE();
    STAGE_A1(av0, kk);
    BAR_PRE_COMPUTE();
    COMPUTE_HALF(0, bf0);
    ISSUE_BFC(bf0, 0, kk + 1);              // kk+1 <= 23 always (kk even)
    COMPUTE_HALF(1, bf1);
    ISSUE_BFC(bf1, 1, kk + 1);
    // ---- odd ----
    BAR_PRE_STAGE();
    STAGE_A1(av1, kk + 1);
    BAR_PRE_COMPUTE();
    if (kk + 2 < KSTEPS) {
      ISSUE_A(av0, kk + 2);
      ISSUE_A(av1, kk + 3);
    }
    COMPUTE_HALF(0, bf0);
    if (kk + 2 < KSTEPS) ISSUE_BFC(bf0, 0, kk + 2);
    COMPUTE_HALF(1, bf1);
    if (kk + 2 < KSTEPS) ISSUE_BFC(bf1, 1, kk + 2);
  }
#undef STAGE_A1
  WRITE_P();
}

// ---------------------------------------------------------------------------
// gemm2: bf16 A-tiles (Alds images) linear copy + staged B (old layout from
// gemm_y) + asm MFMA. Verbatim R12-validated structure.
// ---------------------------------------------------------------------------
__global__ __launch_bounds__(256, 3) void gemm2_kernel(
    const unsigned short* __restrict__ Aws, const unsigned short* __restrict__ Bws,
    unsigned short* __restrict__ Pp)
{
  __shared__ __align__(16) unsigned short Alds[64 * 64];
  __shared__ __align__(16) unsigned short Blds[256 * 64];
  GEMM_IDX();
  const char* aTile0 = (const char*)Aws + ((size_t)(s * 96 + mb) * 24) * 8192;
  const unsigned short* bBase = Bws + (size_t)tBase * 2048 * 8 + (size_t)tid * 8;

  DECL_ACC();
  u16x8 av0[2], av1[2];
  u16x8 bv[8];

#define ISSUE_A2(SET, KK) do {                                                 \
    const char* at = aTile0 + (size_t)(KK) * 8192 + (size_t)tid * 32;          \
    SET[0] = *(const u16x8*)(at);                                              \
    SET[1] = *(const u16x8*)(at + 16);                                         \
  } while (0)

#define STAGE_A2(SET) do {                                                     \
    *(u16x8*)((char*)Alds + (size_t)tid * 32) = SET[0];                        \
    *(u16x8*)((char*)Alds + (size_t)tid * 32 + 16) = SET[1];                   \
  } while (0)

#define ISSUE_B2(KK) do {                                                      \
    _Pragma("unroll")                                                          \
    for (int c = 0; c < 8; ++c)                                                \
      bv[c] = *(const u16x8*)(bBase + (size_t)(KK) * 2048 * 8 + c * 256 * 8);  \
  } while (0)

#define STAGE_B2() do {                                                        \
    _Pragma("unroll")                                                          \
    for (int c = 0; c < 8; ++c)                                                \
      *(u16x8*)(Blds + ((size_t)c * 256 + tid) * 8) = bv[c];                   \
  } while (0)

#define COMPUTE2() do {                                                        \
    _Pragma("unroll")                                                          \
    for (int ks = 0; ks < 2; ++ks) {                                           \
      u16x8 af[4], bfr[4];                                                     \
      _Pragma("unroll")                                                        \
      for (int m = 0; m < 4; ++m) {                                            \
        int row = m * 16 + (lane & 15);                                        \
        int off = (ks * 64 + ((lane >> 4) << 4)) ^ ((row & 7) << 4);           \
        af[m] = *(const u16x8*)((const char*)Alds + row * 128 + off);          \
      }                                                                        \
      _Pragma("unroll")                                                        \
      for (int n = 0; n < 4; ++n) {                                            \
        int row = wave * 64 + n * 16 + (lane & 15);                            \
        int off = (ks * 64 + ((lane >> 4) << 4)) ^ ((row & 7) << 4);           \
        bfr[n] = *(const u16x8*)((const char*)Blds + row * 128 + off);         \
      }                                                                        \
      _Pragma("unroll")                                                        \
      for (int m = 0; m < 4; ++m)                                              \
        _Pragma("unroll")                                                      \
        for (int n = 0; n < 4; ++n)                                            \
          mfma_bf16(acc[m][n], af[m], bfr[n]);                                 \
    } } while (0)

  ISSUE_A2(av0, 0);
  ISSUE_B2(0);
  ISSUE_A2(av1, 1);

  for (int kk = 0; kk < KSTEPS; kk += 2) {
    BAR_PRE_STAGE();
    STAGE_A2(av0);
    STAGE_B2();
    BAR_PRE_COMPUTE();
    ISSUE_B2(kk + 1);
    if (kk + 2 < KSTEPS) ISSUE_A2(av0, kk + 2);
    COMPUTE2();
    BAR_PRE_STAGE();
    STAGE_A2(av1);
    STAGE_B2();
    BAR_PRE_COMPUTE();
    if (kk + 2 < KSTEPS) ISSUE_B2(kk + 2);
    if (kk + 3 < KSTEPS) ISSUE_A2(av1, kk + 3);
    COMPUTE2();
  }
#undef ISSUE_A2
#undef STAGE_A2
#undef ISSUE_B2
#undef STAGE_B2
#undef COMPUTE2
  WRITE_P();
}

// ---------------------------------------------------------------------------
// gemm2 fallback (no handoff): fp32 adj A + staged old-layout B + asm MFMA
// (= validated R12 gemm_adj_kernel).
// ---------------------------------------------------------------------------
__global__ __launch_bounds__(256, 3) void gemm2_fp32_kernel(
    const float* __restrict__ adj, const unsigned short* __restrict__ Bws,
    unsigned short* __restrict__ Pp)
{
  __shared__ __align__(16) unsigned short Alds[64 * 64];
  __shared__ __align__(16) unsigned short Blds[256 * 64];
  GEMM_IDX();
  const int rrel = kbase / NN;
  const int jb   = kbase % NN;
  const float* aRow = adj + (size_t)rrel * NN * NN
                      + (size_t)(i0 + (tid >> 4)) * NN + jb + (tid & 15) * 4;
  const unsigned short* bBase = Bws + (size_t)tBase * 2048 * 8 + (size_t)tid * 8;

  DECL_ACC();
  f32x4 av0[4], av1[4];
  u16x8 bv[8];

#define STAGE_AF(SET) do {                                                     \
    _Pragma("unroll")                                                          \
    for (int it = 0; it < 4; ++it) {                                           \
      int row = (tid >> 4) + it * 16;                                          \
      int off = ((tid & 15) * 8) ^ ((row & 7) << 4);                           \
      u16x4 w;                                                                 \
      w[0] = f2bf(SET[it].x); w[1] = f2bf(SET[it].y);                          \
      w[2] = f2bf(SET[it].z); w[3] = f2bf(SET[it].w);                          \
      *(u16x4*)((char*)Alds + row * 128 + off) = w;                            \
    } } while (0)

#define ISSUE_BF2(KK) do {                                                     \
    _Pragma("unroll")                                                          \
    for (int c = 0; c < 8; ++c)                                                \
      bv[c] = *(const u16x8*)(bBase + (size_t)(KK) * 2048 * 8 + c * 256 * 8);  \
  } while (0)

#define STAGE_BF2() do {                                                       \
    _Pragma("unroll")                                                          \
    for (int c = 0; c < 8; ++c)                                                \
      *(u16x8*)(Blds + ((size_t)c * 256 + tid) * 8) = bv[c];                   \
  } while (0)

#define COMPUTEF() do {                                                        \
    _Pragma("unroll")                                                          \
    for (int ks = 0; ks < 2; ++ks) {                                           \
      u16x8 af[4], bfr[4];                                                     \
      _Pragma("unroll")                                                        \
      for (int m = 0; m < 4; ++m) {                                            \
        int row = m * 16 + (lane & 15);                                        \
        int off = (ks * 64 + ((lane >> 4) << 4)) ^ ((row & 7) << 4);           \
        af[m] = *(const u16x8*)((const char*)Alds + row * 128 + off);          \
      }                                                                        \
      _Pragma("unroll")                                                        \
      for (int n = 0; n < 4; ++n) {                                            \
        int row = wave * 64 + n * 16 + (lane & 15);                            \
        int off = (ks * 64 + ((lane >> 4) << 4)) ^ ((row & 7) << 4);           \
        bfr[n] = *(const u16x8*)((const char*)Blds + row * 128 + off);         \
      }                                                                        \
      _Pragma("unroll")                                                        \
      for (int m = 0; m < 4; ++m)                                              \
        _Pragma("unroll")                                                      \
        for (int n = 0; n < 4; ++n)                                            \
          mfma_bf16(acc[m][n], af[m], bfr[n]);                                 \
    } } while (0)

  ISSUE_A(av0, 0);
  ISSUE_BF2(0);
  ISSUE_A(av1, 1);

  for (int kk = 0; kk < KSTEPS; kk += 2) {
    BAR_PRE_STAGE();
    STAGE_AF(av0);
    STAGE_BF2();
    BAR_PRE_COMPUTE();
    ISSUE_BF2(kk + 1);
    if (kk + 2 < KSTEPS) ISSUE_A(av0, kk + 2);
    COMPUTEF();
    BAR_PRE_STAGE();
    STAGE_AF(av1);
    STAGE_BF2();
    BAR_PRE_COMPUTE();
    if (kk + 2 < KSTEPS) ISSUE_BF2(kk + 2);
    if (kk + 3 < KSTEPS) ISSUE_A(av1, kk + 3);
    COMPUTEF();
  }
#undef STAGE_AF
#undef ISSUE_BF2
#undef STAGE_BF2
#undef COMPUTEF
  WRITE_P();
}

// ---------------------------------------------------------------------------
// gemm_y: Y_r = x @ W2_r (K=256). Output in old B-operand layout (verbatim
// validated R5/R9 kernel, asm MFMA).
// ---------------------------------------------------------------------------
__global__ __launch_bounds__(256, 2) void gemm_y_kernel(
    const unsigned short* __restrict__ xws, const unsigned short* __restrict__ w2ws,
    unsigned short* __restrict__ B2ws)
{
  __shared__ __align__(16) unsigned short Alds[64 * 64];
  __shared__ __align__(16) unsigned short Blds[256 * 64];
  const int tid  = threadIdx.x;
  const int lane = tid & 63;
  const int wave = tid >> 6;
  const int mb = blockIdx.x;
  const int r  = blockIdx.y;

  f32x4 acc[4][4];
#pragma unroll
  for (int m = 0; m < 4; ++m)
#pragma unroll
    for (int n = 0; n < 4; ++n) acc[m][n] = (f32x4){0.f, 0.f, 0.f, 0.f};

  for (int dt = 0; dt < 4; ++dt) {
    u16x8 avv[2];
    avv[0] = *(const u16x8*)(xws + (((size_t)(mb * 4 + dt)) * 512 + tid) * 8);
    avv[1] = *(const u16x8*)(xws + (((size_t)(mb * 4 + dt)) * 512 + 256 + tid) * 8);
    u16x8 bv[8];
#pragma unroll
    for (int c = 0; c < 8; ++c)
      bv[c] = *(const u16x8*)(w2ws + (((size_t)(r * 4 + dt)) * 2048 + c * 256 + tid) * 8);
    __syncthreads();
    *(u16x8*)(Alds + (size_t)tid * 8) = avv[0];
    *(u16x8*)(Alds + ((size_t)256 + tid) * 8) = avv[1];
#pragma unroll
    for (int c = 0; c < 8; ++c)
      *(u16x8*)(Blds + ((size_t)c * 256 + tid) * 8) = bv[c];
    __syncthreads();
#pragma unroll
    for (int ks = 0; ks < 2; ++ks) {
      u16x8 af[4], bfr[4];
#pragma unroll
      for (int m = 0; m < 4; ++m) {
        int row = m * 16 + (lane & 15);
        int off = (ks * 64 + ((lane >> 4) << 4)) ^ ((row & 7) << 4);
        af[m] = *(const u16x8*)((const char*)Alds + row * 128 + off);
      }
#pragma unroll
      for (int n = 0; n < 4; ++n) {
        int row = wave * 64 + n * 16 + (lane & 15);
        int off = (ks * 64 + ((lane >> 4) << 4)) ^ ((row & 7) << 4);
        bfr[n] = *(const u16x8*)((const char*)Blds + row * 128 + off);
      }
#pragma unroll
      for (int m = 0; m < 4; ++m)
#pragma unroll
        for (int n = 0; n < 4; ++n)
          mfma_bf16(acc[m][n], af[m], bfr[n]);
    }
  }
  // emit Y in old B-operand layout: chunk(t=r*96+mb, h, pos), pos = scont^(h&7)
  const int tg = r * 96 + mb;
#pragma unroll
  for (int m = 0; m < 4; ++m) {
    int scont = m * 2 + ((lane >> 4) >> 1);
    int e0    = ((lane >> 4) & 1) * 4;
#pragma unroll
    for (int n = 0; n < 4; ++n) {
      int h   = wave * 64 + n * 16 + (lane & 15);
      int pos = scont ^ (h & 7);
      u16x4 v;
      v[0] = f2bf(acc[m][n][0]); v[1] = f2bf(acc[m][n][1]);
      v[2] = f2bf(acc[m][n][2]); v[3] = f2bf(acc[m][n][3]);
      *(u16x4*)(B2ws + (((size_t)tg * 2048 + h * 8 + pos) * 8 + e0)) = v;
    }
  }
}

// ---------------------------------------------------------------------------
// reduce1: sum_s P[s] -> x = relu -> bf16 pre-swizzled A-tiles (xws)
//          + fused column-sum of out1 into fin[0..255]
// ---------------------------------------------------------------------------
__global__ void reduce1_kernel(const unsigned short* __restrict__ Pp,
                               unsigned short* __restrict__ xws,
                               float* __restrict__ fin)
{
  __shared__ float csm[8][256];
  const int tid = threadIdx.x;
  const int b   = blockIdx.x;
  const int hc  = tid & 31;
  const int rg  = tid >> 5;
  const int dt    = hc >> 3;
  const int scont = hc & 7;
  float cs[8] = {0.f, 0.f, 0.f, 0.f, 0.f, 0.f, 0.f, 0.f};
  for (int k = 0; k < 8; ++k) {
    int i = b * 64 + rg + k * 8;
    float sv[8] = {0.f, 0.f, 0.f, 0.f, 0.f, 0.f, 0.f, 0.f};
#pragma unroll
    for (int s = 0; s < SPLIT; ++s) {
      u16x8 v = *(const u16x8*)(Pp + ((size_t)s * NN + i) * HH + hc * 8);
#pragma unroll
      for (int e = 0; e < 8; ++e) sv[e] += bf2f(v[e]);
    }
    u16x8 xv;
#pragma unroll
    for (int e = 0; e < 8; ++e) {
      cs[e] += sv[e];
      xv[e] = f2bf(fmaxf(sv[e], 0.f));
    }
    int pos = scont ^ (i & 7);
    *(u16x8*)(xws + (((size_t)(b * 4 + dt)) * 512 + (i & 63) * 8 + pos) * 8) = xv;
  }
#pragma unroll
  for (int e = 0; e < 8; ++e) csm[rg][hc * 8 + e] = cs[e];
  __syncthreads();
  float v = 0.f;
#pragma unroll
  for (int r8 = 0; r8 < 8; ++r8) v += csm[r8][tid];
  atomicAdd(&fin[tid], v);
}

// reduce2: sum_s P[s] -> out2 fp32 + fused column-sum into fin[256..511]
__global__ void reduce2_kernel(const unsigned short* __restrict__ Pp,
                               float* __restrict__ outp,
                               float* __restrict__ fin)
{
  __shared__ float csm[8][256];
  const int tid = threadIdx.x;
  const int b   = blockIdx.x;
  const int hc  = tid & 31;
  const int rg  = tid >> 5;
  float cs[8] = {0.f, 0.f, 0.f, 0.f, 0.f, 0.f, 0.f, 0.f};
  for (int k = 0; k < 8; ++k) {
    int i = b * 64 + rg + k * 8;
    float sv[8] = {0.f, 0.f, 0.f, 0.f, 0.f, 0.f, 0.f, 0.f};
#pragma unroll
    for (int s = 0; s < SPLIT; ++s) {
      u16x8 v = *(const u16x8*)(Pp + ((size_t)s * NN + i) * HH + hc * 8);
#pragma unroll
      for (int e = 0; e < 8; ++e) sv[e] += bf2f(v[e]);
    }
    float* o = outp + (size_t)i * HH + hc * 8;
    *(f32x4*)o = (f32x4){sv[0], sv[1], sv[2], sv[3]};
    *(f32x4*)(o + 4) = (f32x4){sv[4], sv[5], sv[6], sv[7]};
#pragma unroll
    for (int e = 0; e < 8; ++e) cs[e] += sv[e];
  }
#pragma unroll
  for (int e = 0; e < 8; ++e) csm[rg][hc * 8 + e] = cs[e];
  __syncthreads();
  float v = 0.f;
#pragma unroll
  for (int r8 = 0; r8 < 8; ++r8) v += csm[r8][tid];
  atomicAdd(&fin[256 + tid], v);
}

// ---------------------------------------------------------------------------
extern "C" void kernel_launch(void* const* d_in, const int* in_sizes, int n_in,
                              void* d_out, int out_size, void* d_ws, size_t ws_size,
                              hipStream_t stream)
{
  const float* adj = (const float*)d_in[0];
  const float* bw1 = (const float*)d_in[1];
  const float* bc1 = (const float*)d_in[2];
  const float* bw2 = (const float*)d_in[3];
  const float* bc2 = (const float*)d_in[4];
  float* out2 = (float*)d_out;                       // 6144*256 fp32
  float* fin  = (float*)d_out + (size_t)NN * HH;     // 512 fp32

  char* ws = (char*)d_ws;
  unsigned short* Pp   = (unsigned short*)(ws + 0);          // 25165824 B
  unsigned short* B1ws = (unsigned short*)(ws + 25165824);   //  6291456 B
  unsigned short* B2ws = (unsigned short*)(ws + 31457280);   //  6291456 B
  unsigned short* xws  = (unsigned short*)(ws + 37748736);   //  3145728 B
  unsigned short* w2ws = (unsigned short*)(ws + 40894464);   //   262144 B
  unsigned short* Aws  = (unsigned short*)(ws + 41943040);   // 150994944 B (end 192937984)
  const bool handoff = (ws_size >= (size_t)192937984);

  prep_kernel<<<202, 256, 0, stream>>>(bw1, bc1, bw2, bc2, B1ws, w2ws, fin);
  if (handoff) {
    gemm1_kernel<true><<<768, 256, 0, stream>>>(adj, B1ws, Pp, Aws);
    reduce1_kernel<<<96, 256, 0, stream>>>(Pp, xws, fin);
    gemm_y_kernel<<<dim3(96, 2), 256, 0, stream>>>(xws, w2ws, B2ws);
    gemm2_kernel<<<768, 256, 0, stream>>>(Aws, B2ws, Pp);
  } else {
    gemm1_kernel<false><<<768, 256, 0, stream>>>(adj, B1ws, Pp, (unsigned short*)ws);
    reduce1_kernel<<<96, 256, 0, stream>>>(Pp, xws, fin);
    gemm_y_kernel<<<dim3(96, 2), 256, 0, stream>>>(xws, w2ws, B2ws);
    gemm2_fp32_kernel<<<768, 256, 0, stream>>>(adj, B2ws, Pp);
  }
  reduce2_kernel<<<96, 256, 0, stream>>>(Pp, out2, fin);
}

// Round 18
// 189.810 us; speedup vs baseline: 1.1607x; 1.0720x over previous
//
#include <hip/hip_runtime.h>

// RGCN restructured (FINAL = validated R12 config, best measured 189.8 us):
//   out1 = A @ W1,   A[i, r*N+j] = adj[r,i,j]   (6144 x 12288) @ (12288 x 256)
//   out2 = A @ Y,    Y[r*N+j, h] = (relu(out1) @ W2_r)[j,h]
//   final[h] = sum_i out1[i,h] ; final[256+h] = sum_i out2[i,h]
// Structure: split-K S=8 bf16-MFMA gemms (staged swizzled-LDS A + LDS B,
// 2-deep A register prefetch, raw T4 barriers, XCD-affine s=bid&7), bf16
// P partials + fused reduces, A-tile bf16 handoff gemm1->gemm2.
// Direct-global-B rejected empirically (R14: 220us strided; R17: 203us
// coalesced) — staged-LDS B with register prefetch wins on this structure.

#define NN 6144
#define HH 256
#define SPLIT 8
#define KCHUNK 1536   // (2*NN)/SPLIT
#define KSTEPS 24     // KCHUNK/64

typedef __attribute__((ext_vector_type(4))) float f32x4;
typedef __attribute__((ext_vector_type(8))) unsigned short u16x8;
typedef __attribute__((ext_vector_type(4))) unsigned short u16x4;

__device__ __forceinline__ unsigned short f2bf(float f) {
  unsigned int u = __float_as_uint(f);
  u += 0x7FFFu + ((u >> 16) & 1u);   // RNE
  return (unsigned short)(u >> 16);
}
__device__ __forceinline__ float bf2f(unsigned short h) {
  return __uint_as_float(((unsigned int)h) << 16);
}

__device__ __forceinline__ void mfma_bf16(f32x4& d, u16x8 a, u16x8 b) {
  asm("v_mfma_f32_16x16x32_bf16 %0, %1, %2, %0" : "+v"(d) : "v"(a), "v"(b));
}

// Raw barriers (T4, validated R9): no vmcnt drain across K-steps.
#define BAR_PRE_STAGE()   asm volatile("s_barrier" ::: "memory")
#define BAR_PRE_COMPUTE() asm volatile("s_waitcnt lgkmcnt(0)\n\ts_barrier" ::: "memory")

// ---------------------------------------------------------------------------
// prep: fused {zero fin} + {wgen W1: 192 tiles} + {wgen W2: 8 tiles}.
// out[t*2048 + h*8 + sp] holds W[k = t*64 + (sp^(h&7))*8 + e][h]  (validated)
// ---------------------------------------------------------------------------
__global__ void prep_kernel(const float* __restrict__ bw1, const float* __restrict__ bc1,
                            const float* __restrict__ bw2, const float* __restrict__ bc2,
                            unsigned short* __restrict__ B1ws, unsigned short* __restrict__ w2ws,
                            float* __restrict__ fin)
{
  const int b   = blockIdx.x;
  const int tid = threadIdx.x;
  if (b >= 200) { fin[(b - 200) * 256 + tid] = 0.f; return; }

  const float* basis; const float* bc; unsigned short* outw;
  int tilesPerR, jdim, t;
  if (b < 192) { basis = bw1; bc = bc1; outw = B1ws; tilesPerR = 96; jdim = NN; t = b; }
  else         { basis = bw2; bc = bc2; outw = w2ws; tilesPerR = 4;  jdim = HH; t = b - 192; }

  __shared__ unsigned short wt[64][265];
  const int r  = t / tilesPerR;
  const int jt = t % tilesPerR;
  const float c0 = bc[r * 2 + 0];
  const float c1 = bc[r * 2 + 1];
  const float* b0 = basis + (size_t)jt * 64 * HH;
  const float* b1 = basis + (size_t)jdim * HH + (size_t)jt * 64 * HH;
#pragma unroll
  for (int k = 0; k < 16; ++k) {
    int idx = tid + k * 256;
    int row = idx >> 6;
    int c4  = (idx & 63) * 4;
    f32x4 v0 = *(const f32x4*)(b0 + (size_t)row * HH + c4);
    f32x4 v1 = *(const f32x4*)(b1 + (size_t)row * HH + c4);
    wt[row][c4 + 0] = f2bf(c0 * v0.x + c1 * v1.x);
    wt[row][c4 + 1] = f2bf(c0 * v0.y + c1 * v1.y);
    wt[row][c4 + 2] = f2bf(c0 * v0.z + c1 * v1.z);
    wt[row][c4 + 3] = f2bf(c0 * v0.w + c1 * v1.w);
  }
  __syncthreads();
#pragma unroll
  for (int k = 0; k < 8; ++k) {
    int chunk = tid + k * 256;
    int h  = chunk >> 3;
    int sp = chunk & 7;
    int j0 = (sp ^ (h & 7)) * 8;
    u16x8 v;
#pragma unroll
    for (int e = 0; e < 8; ++e) v[e] = wt[j0 + e][h];
    *(u16x8*)(outw + ((size_t)t * 2048 + chunk) * 8) = v;
  }
}

// ---------------------------------------------------------------------------
// Shared macros for the gemm family (BM=64, BN=256, BK=64).
// ---------------------------------------------------------------------------
#define GEMM_PROLOGUE_COMMON()                                                 \
  const int tid  = threadIdx.x;                                                \
  const int lane = tid & 63;                                                   \
  const int wave = tid >> 6;                                                   \
  const int bid  = blockIdx.x;                                                 \
  const int s    = bid & 7;          /* XCD-affine (validated R10) */          \
  const int mb   = bid >> 3;                                                   \
  const int i0 = mb * 64;                                                      \
  const int kbase = s * KCHUNK;                                                \
  const int tBase = kbase / 64;                                                \
  const unsigned short* bBase = Bws + (size_t)tBase * 2048 * 8 + (size_t)tid * 8;

#define DECL_ACC()                                                             \
  f32x4 acc[4][4];                                                             \
  _Pragma("unroll")                                                            \
  for (int m = 0; m < 4; ++m)                                                  \
    _Pragma("unroll")                                                          \
    for (int n = 0; n < 4; ++n) acc[m][n] = (f32x4){0.f, 0.f, 0.f, 0.f};

#define ISSUE_B(KK) do {                                                       \
    _Pragma("unroll")                                                          \
    for (int c = 0; c < 8; ++c)                                                \
      bv[c] = *(const u16x8*)(bBase + (size_t)(KK) * 2048 * 8 + c * 256 * 8);  \
  } while (0)

#define STAGE_B() do {                                                         \
    _Pragma("unroll")                                                          \
    for (int c = 0; c < 8; ++c)                                                \
      *(u16x8*)(Blds + ((size_t)c * 256 + tid) * 8) = bv[c];                   \
  } while (0)

#define COMPUTE() do {                                                         \
    _Pragma("unroll")                                                          \
    for (int ks = 0; ks < 2; ++ks) {                                           \
      u16x8 af[4], bfr[4];                                                     \
      _Pragma("unroll")                                                        \
      for (int m = 0; m < 4; ++m) {                                            \
        int row = m * 16 + (lane & 15);                                        \
        int off = (ks * 64 + ((lane >> 4) << 4)) ^ ((row & 7) << 4);           \
        af[m] = *(const u16x8*)((const char*)Alds + row * 128 + off);          \
      }                                                                        \
      _Pragma("unroll")                                                        \
      for (int n = 0; n < 4; ++n) {                                            \
        int row = wave * 64 + n * 16 + (lane & 15);                            \
        int off = (ks * 64 + ((lane >> 4) << 4)) ^ ((row & 7) << 4);           \
        bfr[n] = *(const u16x8*)((const char*)Blds + row * 128 + off);         \
      }                                                                        \
      _Pragma("unroll")                                                        \
      for (int m = 0; m < 4; ++m)                                              \
        _Pragma("unroll")                                                      \
        for (int n = 0; n < 4; ++n)                                            \
          mfma_bf16(acc[m][n], af[m], bfr[n]);                                 \
    } } while (0)

#define WRITE_P() do {                                                         \
    unsigned short* P = Pp + ((size_t)s * NN + i0) * HH;                       \
    _Pragma("unroll")                                                          \
    for (int m = 0; m < 4; ++m)                                                \
      _Pragma("unroll")                                                        \
      for (int n = 0; n < 4; ++n) {                                            \
        int col = wave * 64 + n * 16 + (lane & 15);                            \
        _Pragma("unroll")                                                      \
        for (int q = 0; q < 4; ++q) {                                          \
          int row = m * 16 + ((lane >> 4) << 2) + q;                           \
          P[(size_t)row * HH + col] = f2bf(acc[m][n][q]);                      \
        }                                                                      \
      } } while (0)

#define ISSUE_A(SET, KK) do {                                                  \
    _Pragma("unroll")                                                          \
    for (int it = 0; it < 4; ++it)                                             \
      SET[it] = *(const f32x4*)(aRow + (size_t)it * 16 * NN + (KK) * 64);      \
  } while (0)

// ---------------------------------------------------------------------------
// gemm_adj_store: fp32 adj in; ALSO stores the converted+swizzled Alds image
// (8 KB per K-step) to Aws for gemm2's consumption.
// ---------------------------------------------------------------------------
__global__ __launch_bounds__(256, 3) void gemm_adj_store_kernel(
    const float* __restrict__ adj, const unsigned short* __restrict__ Bws,
    unsigned short* __restrict__ Pp, unsigned short* __restrict__ Aws)
{
  __shared__ __align__(16) unsigned short Alds[64 * 64];
  __shared__ __align__(16) unsigned short Blds[256 * 64];
  GEMM_PROLOGUE_COMMON();
  const int rrel = kbase / NN;
  const int jb   = kbase % NN;
  const float* aRow = adj + (size_t)rrel * NN * NN
                      + (size_t)(i0 + (tid >> 4)) * NN + jb + (tid & 15) * 4;
  char* aTile0 = (char*)Aws + ((size_t)(s * 96 + mb) * 24) * 8192;

  DECL_ACC();
  f32x4 av0[4], av1[4];
  u16x8 bv[8];

#define STAGE_A_ST(SET, KK) do {                                               \
    char* at = aTile0 + (size_t)(KK) * 8192;                                   \
    _Pragma("unroll")                                                          \
    for (int it = 0; it < 4; ++it) {                                           \
      int row = (tid >> 4) + it * 16;                                          \
      int off = ((tid & 15) * 8) ^ ((row & 7) << 4);                           \
      u16x4 w;                                                                 \
      w[0] = f2bf(SET[it].x); w[1] = f2bf(SET[it].y);                          \
      w[2] = f2bf(SET[it].z); w[3] = f2bf(SET[it].w);                          \
      *(u16x4*)((char*)Alds + row * 128 + off) = w;                            \
      *(u16x4*)(at + row * 128 + off) = w;                                     \
    } } while (0)

  ISSUE_A(av0, 0);
  ISSUE_A(av1, 1);
  ISSUE_B(0);

  for (int kk = 0; kk < KSTEPS; kk += 2) {
    BAR_PRE_STAGE();
    STAGE_A_ST(av0, kk);
    STAGE_B();
    BAR_PRE_COMPUTE();
    ISSUE_B(kk + 1);
    COMPUTE();
    BAR_PRE_STAGE();
    STAGE_A_ST(av1, kk + 1);
    STAGE_B();
    BAR_PRE_COMPUTE();
    if (kk + 2 < KSTEPS) {
      ISSUE_A(av0, kk + 2);
      ISSUE_A(av1, kk + 3);
      ISSUE_B(kk + 2);
    }
    COMPUTE();
  }
#undef STAGE_A_ST
  WRITE_P();
}

// ---------------------------------------------------------------------------
// gemm_adj_bf: bf16 A-tiles in (exact Alds images) -> linear identity copy.
// ---------------------------------------------------------------------------
__global__ __launch_bounds__(256, 3) void gemm_adj_bf_kernel(
    const unsigned short* __restrict__ Aws, const unsigned short* __restrict__ Bws,
    unsigned short* __restrict__ Pp)
{
  __shared__ __align__(16) unsigned short Alds[64 * 64];
  __shared__ __align__(16) unsigned short Blds[256 * 64];
  GEMM_PROLOGUE_COMMON();
  const char* aTile0 = (const char*)Aws + ((size_t)(s * 96 + mb) * 24) * 8192;

  DECL_ACC();
  u16x8 av0[2], av1[2];
  u16x8 bv[8];

#define ISSUE_A2(SET, KK) do {                                                 \
    const char* at = aTile0 + (size_t)(KK) * 8192 + (size_t)tid * 32;          \
    SET[0] = *(const u16x8*)(at);                                              \
    SET[1] = *(const u16x8*)(at + 16);                                         \
  } while (0)

#define STAGE_A2(SET) do {                                                     \
    *(u16x8*)((char*)Alds + (size_t)tid * 32) = SET[0];                        \
    *(u16x8*)((char*)Alds + (size_t)tid * 32 + 16) = SET[1];                   \
  } while (0)

  ISSUE_A2(av0, 0);
  ISSUE_B(0);
  ISSUE_A2(av1, 1);

  for (int kk = 0; kk < KSTEPS; kk += 2) {
    BAR_PRE_STAGE();
    STAGE_A2(av0);
    STAGE_B();
    BAR_PRE_COMPUTE();
    ISSUE_B(kk + 1);
    if (kk + 2 < KSTEPS) ISSUE_A2(av0, kk + 2);
    COMPUTE();
    BAR_PRE_STAGE();
    STAGE_A2(av1);
    STAGE_B();
    BAR_PRE_COMPUTE();
    if (kk + 2 < KSTEPS) ISSUE_B(kk + 2);
    if (kk + 3 < KSTEPS) ISSUE_A2(av1, kk + 3);
    COMPUTE();
  }
#undef ISSUE_A2
#undef STAGE_A2
  WRITE_P();
}

// ---------------------------------------------------------------------------
// gemm_adj: validated R11 kernel (fallback path if ws too small).
// ---------------------------------------------------------------------------
__global__ __launch_bounds__(256, 3) void gemm_adj_kernel(
    const float* __restrict__ adj, const unsigned short* __restrict__ Bws,
    unsigned short* __restrict__ Pp)
{
  __shared__ __align__(16) unsigned short Alds[64 * 64];
  __shared__ __align__(16) unsigned short Blds[256 * 64];
  GEMM_PROLOGUE_COMMON();
  const int rrel = kbase / NN;
  const int jb   = kbase % NN;
  const float* aRow = adj + (size_t)rrel * NN * NN
                      + (size_t)(i0 + (tid >> 4)) * NN + jb + (tid & 15) * 4;

  DECL_ACC();
  f32x4 av0[4], av1[4];
  u16x8 bv[8];

#define STAGE_A(SET) do {                                                      \
    _Pragma("unroll")                                                          \
    for (int it = 0; it < 4; ++it) {                                           \
      int row = (tid >> 4) + it * 16;                                          \
      int off = ((tid & 15) * 8) ^ ((row & 7) << 4);                           \
      u16x4 w;                                                                 \
      w[0] = f2bf(SET[it].x); w[1] = f2bf(SET[it].y);                          \
      w[2] = f2bf(SET[it].z); w[3] = f2bf(SET[it].w);                          \
      *(u16x4*)((char*)Alds + row * 128 + off) = w;                            \
    } } while (0)

  ISSUE_A(av0, 0);
  ISSUE_B(0);
  ISSUE_A(av1, 1);

  for (int kk = 0; kk < KSTEPS; kk += 2) {
    BAR_PRE_STAGE();
    STAGE_A(av0);
    STAGE_B();
    BAR_PRE_COMPUTE();
    ISSUE_B(kk + 1);
    if (kk + 2 < KSTEPS) ISSUE_A(av0, kk + 2);
    COMPUTE();
    BAR_PRE_STAGE();
    STAGE_A(av1);
    STAGE_B();
    BAR_PRE_COMPUTE();
    if (kk + 2 < KSTEPS) ISSUE_B(kk + 2);
    if (kk + 3 < KSTEPS) ISSUE_A(av1, kk + 3);
    COMPUTE();
  }
#undef STAGE_A
  WRITE_P();
}

// ---------------------------------------------------------------------------
// gemm_y: Y_r = x @ W2_r (K=256). Output written in B-operand layout.
// (verbatim validated R5/R9 kernel)
// ---------------------------------------------------------------------------
__global__ __launch_bounds__(256, 2) void gemm_y_kernel(
    const unsigned short* __restrict__ xws, const unsigned short* __restrict__ w2ws,
    unsigned short* __restrict__ B2ws)
{
  __shared__ __align__(16) unsigned short Alds[64 * 64];
  __shared__ __align__(16) unsigned short Blds[256 * 64];
  const int tid  = threadIdx.x;
  const int lane = tid & 63;
  const int wave = tid >> 6;
  const int mb = blockIdx.x;
  const int r  = blockIdx.y;

  f32x4 acc[4][4];
#pragma unroll
  for (int m = 0; m < 4; ++m)
#pragma unroll
    for (int n = 0; n < 4; ++n) acc[m][n] = (f32x4){0.f, 0.f, 0.f, 0.f};

  for (int dt = 0; dt < 4; ++dt) {
    u16x8 avv[2];
    avv[0] = *(const u16x8*)(xws + (((size_t)(mb * 4 + dt)) * 512 + tid) * 8);
    avv[1] = *(const u16x8*)(xws + (((size_t)(mb * 4 + dt)) * 512 + 256 + tid) * 8);
    u16x8 bv[8];
#pragma unroll
    for (int c = 0; c < 8; ++c)
      bv[c] = *(const u16x8*)(w2ws + (((size_t)(r * 4 + dt)) * 2048 + c * 256 + tid) * 8);
    __syncthreads();
    *(u16x8*)(Alds + (size_t)tid * 8) = avv[0];
    *(u16x8*)(Alds + ((size_t)256 + tid) * 8) = avv[1];
#pragma unroll
    for (int c = 0; c < 8; ++c)
      *(u16x8*)(Blds + ((size_t)c * 256 + tid) * 8) = bv[c];
    __syncthreads();
#pragma unroll
    for (int ks = 0; ks < 2; ++ks) {
      u16x8 af[4], bfr[4];
#pragma unroll
      for (int m = 0; m < 4; ++m) {
        int row = m * 16 + (lane & 15);
        int off = (ks * 64 + ((lane >> 4) << 4)) ^ ((row & 7) << 4);
        af[m] = *(const u16x8*)((const char*)Alds + row * 128 + off);
      }
#pragma unroll
      for (int n = 0; n < 4; ++n) {
        int row = wave * 64 + n * 16 + (lane & 15);
        int off = (ks * 64 + ((lane >> 4) << 4)) ^ ((row & 7) << 4);
        bfr[n] = *(const u16x8*)((const char*)Blds + row * 128 + off);
      }
#pragma unroll
      for (int m = 0; m < 4; ++m)
#pragma unroll
        for (int n = 0; n < 4; ++n)
          mfma_bf16(acc[m][n], af[m], bfr[n]);
    }
  }
  // emit Y in B-operand layout: chunk(t=r*96+mb, h, pos) gets k-slot pos^(h&7)
  const int tg = r * 96 + mb;
#pragma unroll
  for (int m = 0; m < 4; ++m) {
    int scont = m * 2 + ((lane >> 4) >> 1);
    int e0    = ((lane >> 4) & 1) * 4;
#pragma unroll
    for (int n = 0; n < 4; ++n) {
      int h   = wave * 64 + n * 16 + (lane & 15);
      int pos = scont ^ (h & 7);
      u16x4 v;
      v[0] = f2bf(acc[m][n][0]); v[1] = f2bf(acc[m][n][1]);
      v[2] = f2bf(acc[m][n][2]); v[3] = f2bf(acc[m][n][3]);
      *(u16x4*)(B2ws + (((size_t)tg * 2048 + h * 8 + pos) * 8 + e0)) = v;
    }
  }
}

// ---------------------------------------------------------------------------
// reduce1: sum_s P[s] -> x = relu -> bf16 pre-swizzled A-tiles (xws)
//          + fused column-sum of out1 into fin[0..255]
// ---------------------------------------------------------------------------
__global__ void reduce1_kernel(const unsigned short* __restrict__ Pp,
                               unsigned short* __restrict__ xws,
                               float* __restrict__ fin)
{
  __shared__ float csm[8][256];
  const int tid = threadIdx.x;
  const int b   = blockIdx.x;
  const int hc  = tid & 31;
  const int rg  = tid >> 5;
  const int dt    = hc >> 3;
  const int scont = hc & 7;
  float cs[8] = {0.f, 0.f, 0.f, 0.f, 0.f, 0.f, 0.f, 0.f};
  for (int k = 0; k < 8; ++k) {
    int i = b * 64 + rg + k * 8;
    float sv[8] = {0.f, 0.f, 0.f, 0.f, 0.f, 0.f, 0.f, 0.f};
#pragma unroll
    for (int s = 0; s < SPLIT; ++s) {
      u16x8 v = *(const u16x8*)(Pp + ((size_t)s * NN + i) * HH + hc * 8);
#pragma unroll
      for (int e = 0; e < 8; ++e) sv[e] += bf2f(v[e]);
    }
    u16x8 xv;
#pragma unroll
    for (int e = 0; e < 8; ++e) {
      cs[e] += sv[e];
      xv[e] = f2bf(fmaxf(sv[e], 0.f));
    }
    int pos = scont ^ (i & 7);
    *(u16x8*)(xws + (((size_t)(b * 4 + dt)) * 512 + (i & 63) * 8 + pos) * 8) = xv;
  }
#pragma unroll
  for (int e = 0; e < 8; ++e) csm[rg][hc * 8 + e] = cs[e];
  __syncthreads();
  float v = 0.f;
#pragma unroll
  for (int r8 = 0; r8 < 8; ++r8) v += csm[r8][tid];
  atomicAdd(&fin[tid], v);
}

// reduce2: sum_s P[s] -> out2 fp32 + fused column-sum into fin[256..511]
__global__ void reduce2_kernel(const unsigned short* __restrict__ Pp,
                               float* __restrict__ outp,
                               float* __restrict__ fin)
{
  __shared__ float csm[8][256];
  const int tid = threadIdx.x;
  const int b   = blockIdx.x;
  const int hc  = tid & 31;
  const int rg  = tid >> 5;
  float cs[8] = {0.f, 0.f, 0.f, 0.f, 0.f, 0.f, 0.f, 0.f};
  for (int k = 0; k < 8; ++k) {
    int i = b * 64 + rg + k * 8;
    float sv[8] = {0.f, 0.f, 0.f, 0.f, 0.f, 0.f, 0.f, 0.f};
#pragma unroll
    for (int s = 0; s < SPLIT; ++s) {
      u16x8 v = *(const u16x8*)(Pp + ((size_t)s * NN + i) * HH + hc * 8);
#pragma unroll
      for (int e = 0; e < 8; ++e) sv[e] += bf2f(v[e]);
    }
    float* o = outp + (size_t)i * HH + hc * 8;
    *(f32x4*)o = (f32x4){sv[0], sv[1], sv[2], sv[3]};
    *(f32x4*)(o + 4) = (f32x4){sv[4], sv[5], sv[6], sv[7]};
#pragma unroll
    for (int e = 0; e < 8; ++e) cs[e] += sv[e];
  }
#pragma unroll
  for (int e = 0; e < 8; ++e) csm[rg][hc * 8 + e] = cs[e];
  __syncthreads();
  float v = 0.f;
#pragma unroll
  for (int r8 = 0; r8 < 8; ++r8) v += csm[r8][tid];
  atomicAdd(&fin[256 + tid], v);
}

// ---------------------------------------------------------------------------
extern "C" void kernel_launch(void* const* d_in, const int* in_sizes, int n_in,
                              void* d_out, int out_size, void* d_ws, size_t ws_size,
                              hipStream_t stream)
{
  const float* adj = (const float*)d_in[0];
  const float* bw1 = (const float*)d_in[1];
  const float* bc1 = (const float*)d_in[2];
  const float* bw2 = (const float*)d_in[3];
  const float* bc2 = (const float*)d_in[4];
  float* out2 = (float*)d_out;                       // 6144*256 fp32
  float* fin  = (float*)d_out + (size_t)NN * HH;     // 512 fp32

  char* ws = (char*)d_ws;
  unsigned short* Pp   = (unsigned short*)(ws + 0);          // 25165824 B
  unsigned short* B1ws = (unsigned short*)(ws + 25165824);   //  6291456 B
  unsigned short* B2ws = (unsigned short*)(ws + 31457280);   //  6291456 B
  unsigned short* xws  = (unsigned short*)(ws + 37748736);   //  3145728 B
  unsigned short* w2ws = (unsigned short*)(ws + 40894464);   //   262144 B
  unsigned short* Aws  = (unsigned short*)(ws + 41943040);   // 150994944 B (end 192937984)
  const bool handoff = (ws_size >= (size_t)192937984);

  prep_kernel<<<202, 256, 0, stream>>>(bw1, bc1, bw2, bc2, B1ws, w2ws, fin);
  if (handoff)
    gemm_adj_store_kernel<<<768, 256, 0, stream>>>(adj, B1ws, Pp, Aws);
  else
    gemm_adj_kernel<<<768, 256, 0, stream>>>(adj, B1ws, Pp);
  reduce1_kernel<<<96, 256, 0, stream>>>(Pp, xws, fin);
  gemm_y_kernel<<<dim3(96, 2), 256, 0, stream>>>(xws, w2ws, B2ws);
  if (handoff)
    gemm_adj_bf_kernel<<<768, 256, 0, stream>>>(Aws, B2ws, Pp);
  else
    gemm_adj_kernel<<<768, 256, 0, stream>>>(adj, B2ws, Pp);
  reduce2_kernel<<<96, 256, 0, stream>>>(Pp, out2, fin);
}